// Round 1
// baseline (4707.009 us; speedup 1.0000x reference)
//
#include <hip/hip_runtime.h>
#include <hip/hip_bf16.h>

// Bidirectional LSTM: B=64, T=512, D=512 (feats = x[b,h,t,c] -> k=h*64+c), U=256.
// W: [768,1024] fp32, gates (i,j,f,o), forget bias 1.0. Output [64,512,512] fp32
// (fw units 0..255, bw units 256..511), bw output aligned to time index.

typedef float f32x4 __attribute__((ext_vector_type(4)));
typedef short s16x4 __attribute__((ext_vector_type(4)));
typedef __bf16 bf16x8 __attribute__((ext_vector_type(8)));

__device__ __forceinline__ unsigned short f2bf(float f) {
    union { float f; unsigned int u; } v; v.f = f;
    unsigned int u = v.u;
    u += 0x7FFFu + ((u >> 16) & 1);   // RNE
    return (unsigned short)(u >> 16);
}
__device__ __forceinline__ float bf2f(unsigned short h) {
    union { unsigned int u; float f; } v;
    v.u = ((unsigned int)h) << 16;
    return v.f;
}
__device__ __forceinline__ bf16x8 lds_load8(const unsigned short* p) {
    union { struct { s16x4 a; s16x4 b; } s; bf16x8 v; } u;
    u.s.a = *(const s16x4*)p;
    u.s.b = *(const s16x4*)(p + 4);
    return u.v;
}

// ---------------------------------------------------------------- repack Wrec
__global__ void repack_wrec(const float* __restrict__ Wfw,
                            const float* __restrict__ Wbw,
                            unsigned short* __restrict__ wrec) {
    int i = blockIdx.x * blockDim.x + threadIdx.x;   // 0 .. 2*262144-1
    int dir = i >> 18;
    int j = i & 262143;
    const float* W = dir ? Wbw : Wfw;
    wrec[i] = f2bf(W[512 * 1024 + j]);
}

// ---------------------------------------------------------------- xz GEMM
// C[m,n] = sum_k feats[m,k]*W[k,n] + bias[n];  m=(b*Tc+tl), t=t0+tl
#define BM 128
#define BN 128
#define BK 32
#define ASTR 40   // shorts per LDS row (32 + 8 pad)

__global__ __launch_bounds__(256)
void gemm_xz(const float* __restrict__ x,
             const float* __restrict__ Wfw, const float* __restrict__ Wbw,
             const float* __restrict__ bfw, const float* __restrict__ bbw,
             unsigned short* __restrict__ xz_fw, unsigned short* __restrict__ xz_bw,
             int Tc, int t0f, int t0b) {
    const int dir = blockIdx.z;
    const float* __restrict__ W   = dir ? Wbw : Wfw;
    const float* __restrict__ bias = dir ? bbw : bfw;
    unsigned short* __restrict__ xz = dir ? xz_bw : xz_fw;
    const int t0 = dir ? t0b : t0f;

    __shared__ __align__(16) unsigned short As[BM * ASTR];
    __shared__ __align__(16) unsigned short Bs[BN * ASTR];

    const int tid = threadIdx.x;
    const int m0 = blockIdx.x * BM;
    const int n0 = blockIdx.y * BN;

    const int lane = tid & 63;
    const int wave = tid >> 6;
    const int wm = (wave & 1) * 64;
    const int wn = (wave >> 1) * 64;
    const int mi = lane & 15;
    const int kq = lane >> 4;          // 0..3

    // A staging: thread -> (row, half)
    const int arow = tid >> 1;          // 0..127
    const int ahalf = (tid & 1) * 16;   // k offset 0 / 16
    const int am = m0 + arow;
    const int bb = am / Tc;
    const int tl = am % Tc;
    const int t  = t0 + tl;
    // B staging: thread -> (kk, nc)
    const int kk = tid >> 3;            // 0..31
    const int nc = (tid & 7) * 16;      // 0..112

    f32x4 acc[4][4];
#pragma unroll
    for (int i = 0; i < 4; i++)
#pragma unroll
        for (int j = 0; j < 4; j++) acc[i][j] = (f32x4)0.f;

    for (int kt = 0; kt < 512; kt += BK) {
        // ---- global loads (fp32) ----
        float va[16], vb[16];
        {
            const int kbase = kt + ahalf;             // mult of 16
            const int hh = kbase >> 6;
            const float* px = x + (((size_t)bb * 8 + hh) * 512 + t) * 64 + (kbase & 63);
#pragma unroll
            for (int i = 0; i < 4; i++) {
                f32x4 v = *(const f32x4*)(px + i * 4);
                va[i*4+0] = v[0]; va[i*4+1] = v[1]; va[i*4+2] = v[2]; va[i*4+3] = v[3];
            }
            const float* pw = W + (size_t)(kt + kk) * 1024 + n0 + nc;
#pragma unroll
            for (int i = 0; i < 4; i++) {
                f32x4 v = *(const f32x4*)(pw + i * 4);
                vb[i*4+0] = v[0]; vb[i*4+1] = v[1]; vb[i*4+2] = v[2]; vb[i*4+3] = v[3];
            }
        }
        __syncthreads();   // previous tile consumed
        // ---- LDS stores (bf16) ----
        {
            unsigned short* pa = &As[arow * ASTR + ahalf];
#pragma unroll
            for (int i = 0; i < 4; i++) {
                s16x4 s;
                s[0] = (short)f2bf(va[i*4+0]); s[1] = (short)f2bf(va[i*4+1]);
                s[2] = (short)f2bf(va[i*4+2]); s[3] = (short)f2bf(va[i*4+3]);
                *(s16x4*)(pa + i * 4) = s;
            }
#pragma unroll
            for (int i = 0; i < 16; i++)
                Bs[(nc + i) * ASTR + kk] = f2bf(vb[i]);   // transpose: Bs[n][k]
        }
        __syncthreads();
        // ---- MFMA ----
        bf16x8 afr[4], bfr[4];
#pragma unroll
        for (int mt = 0; mt < 4; mt++)
            afr[mt] = lds_load8(&As[(wm + mt * 16 + mi) * ASTR + kq * 8]);
#pragma unroll
        for (int nt = 0; nt < 4; nt++)
            bfr[nt] = lds_load8(&Bs[(wn + nt * 16 + mi) * ASTR + kq * 8]);
#pragma unroll
        for (int mt = 0; mt < 4; mt++)
#pragma unroll
            for (int nt = 0; nt < 4; nt++)
                acc[mt][nt] = __builtin_amdgcn_mfma_f32_16x16x32_bf16(
                    afr[mt], bfr[nt], acc[mt][nt], 0, 0, 0);
    }

    // ---- epilogue: D row=(lane>>4)*4+r, col=lane&15 ----
    const int col = lane & 15;
    const int rbase = kq * 4;
#pragma unroll
    for (int mt = 0; mt < 4; mt++) {
#pragma unroll
        for (int nt = 0; nt < 4; nt++) {
            const int n = n0 + wn + nt * 16 + col;
            const float bv = bias[n];
#pragma unroll
            for (int r = 0; r < 4; r++) {
                const int mrow = m0 + wm + mt * 16 + rbase + r;
                xz[(size_t)mrow * 1024 + n] = f2bf(acc[mt][nt][r] + bv);
            }
        }
    }
}

// ---------------------------------------------------------------- recurrence
// One workgroup per (dir, batch). 1024 threads: thread g owns gate column g.
__global__ __launch_bounds__(1024)
void rec_step(const unsigned short* __restrict__ xz_fw,
              const unsigned short* __restrict__ xz_bw,
              const unsigned short* __restrict__ wrec,
              float* __restrict__ out,
              float* __restrict__ c_state, float* __restrict__ h_state,
              int Tc, int t0f, int t0b, int first) {
    const int bid = blockIdx.x;
    const int dir = bid >> 6;
    const int b   = bid & 63;
    const unsigned short* __restrict__ Wb = wrec + (size_t)dir * 262144;
    const unsigned short* __restrict__ xz =
        (dir ? xz_bw : xz_fw) + (size_t)b * Tc * 1024;
    const int t0 = dir ? t0b : t0f;

    __shared__ float h_lds[256];
    __shared__ float z_lds[1024];
    const int g = threadIdx.x;

    float c = 0.f;
    if (g < 256) {
        float h0 = 0.f;
        if (!first) {
            c  = c_state[(dir * 64 + b) * 256 + g];
            h0 = h_state[(dir * 64 + b) * 256 + g];
        }
        h_lds[g] = h0;
    }
    __syncthreads();

    const unsigned short* wp = Wb + g;
    for (int s = 0; s < Tc; s++) {
        const int tl = dir ? (Tc - 1 - s) : s;
        const int t  = t0 + tl;

        float a0 = bf2f(xz[(size_t)tl * 1024 + g]);
        float a1 = 0.f;
#pragma unroll 8
        for (int u = 0; u < 256; u += 2) {
            a0 = fmaf(h_lds[u],     bf2f(wp[(size_t)u * 1024]),        a0);
            a1 = fmaf(h_lds[u + 1], bf2f(wp[(size_t)(u + 1) * 1024]), a1);
        }
        z_lds[g] = a0 + a1;
        __syncthreads();

        if (g < 256) {
            const float zi = z_lds[g];
            const float zj = z_lds[256 + g];
            const float zf = z_lds[512 + g] + 1.0f;   // FORGET_BIAS
            const float zo = z_lds[768 + g];
            const float ig = 1.f / (1.f + __expf(-zi));
            const float fg = 1.f / (1.f + __expf(-zf));
            const float og = 1.f / (1.f + __expf(-zo));
            const float jt = tanhf(zj);
            c = fg * c + ig * jt;
            const float h = og * tanhf(c);
            h_lds[g] = h;
            out[((size_t)b * 512 + t) * 512 + dir * 256 + g] = h;
        }
        __syncthreads();
    }
    if (g < 256) {
        c_state[(dir * 64 + b) * 256 + g] = c;
        h_state[(dir * 64 + b) * 256 + g] = h_lds[g];
    }
}

// ---------------------------------------------------------------- launcher
extern "C" void kernel_launch(void* const* d_in, const int* in_sizes, int n_in,
                              void* d_out, int out_size, void* d_ws, size_t ws_size,
                              hipStream_t stream) {
    const float* x   = (const float*)d_in[0];
    const float* Wfw = (const float*)d_in[1];
    const float* bfw = (const float*)d_in[2];
    const float* Wbw = (const float*)d_in[3];
    const float* bbw = (const float*)d_in[4];
    float* out = (float*)d_out;

    // pick largest T-chunk that fits ws
    int Tc = 512;
    while (Tc > 8) {
        size_t need = 2ull * 64 * Tc * 1024 * 2      // xz fw+bw (bf16)
                    + 2ull * 256 * 1024 * 2          // wrec (bf16)
                    + 2ull * 2 * 64 * 256 * 4;       // c,h state
        if (need <= ws_size) break;
        Tc >>= 1;
    }

    unsigned short* xzf  = (unsigned short*)d_ws;
    unsigned short* xzb  = xzf + (size_t)64 * Tc * 1024;
    unsigned short* wrec = xzb + (size_t)64 * Tc * 1024;
    float* cst = (float*)(wrec + 2 * 262144);
    float* hst = cst + 2 * 64 * 256;

    repack_wrec<<<dim3(2048), 256, 0, stream>>>(Wfw, Wbw, wrec);

    const int nCh = 512 / Tc;
    for (int ck = 0; ck < nCh; ck++) {
        const int t0f = ck * Tc;
        const int t0b = 512 - (ck + 1) * Tc;
        gemm_xz<<<dim3(Tc / 2, 8, 2), 256, 0, stream>>>(
            x, Wfw, Wbw, bfw, bbw, xzf, xzb, Tc, t0f, t0b);
        rec_step<<<dim3(128), 1024, 0, stream>>>(
            xzf, xzb, wrec, out, cst, hst, Tc, t0f, t0b, ck == 0);
    }
    (void)in_sizes; (void)n_in; (void)out_size; (void)ws_size;
}

// Round 2
// 3362.976 us; speedup vs baseline: 1.3997x; 1.3997x over previous
//
#include <hip/hip_runtime.h>

// Bidirectional LSTM: B=64, T=512, D=512 (feats k=h*64+c), U=256.
// W: [768,1024] fp32, gate order (i,j,f,o), forget bias 1.0.
// out [64,512,512] fp32 (fw units 0..255, bw 256..511), bw aligned to t.
//
// Structure:
//  init_all : repack recurrent weights -> wrec2[dir][128-col slice][k] f16,
//             zero h double-buffer + barrier counters.
//  gemm_xz  : xz[dir][b][t][1024] = feats@Wx + bias  (f16, MFMA 16x16x32)
//  rec_persist : 16 workgroups (2 dirs x 8 slices). Weights in REGISTERS,
//             h exchanged via MALL-coherent (agent-scope atomic) buffer,
//             per-step spin barrier among the 8 slices of a direction.

typedef float f32x4 __attribute__((ext_vector_type(4)));
typedef _Float16 f16;
typedef _Float16 f16x4 __attribute__((ext_vector_type(4)));
typedef _Float16 f16x8 __attribute__((ext_vector_type(8)));
typedef unsigned long long u64;

// ---------------------------------------------------------------- init
__global__ void init_all(const float* __restrict__ Wfw, const float* __restrict__ Wbw,
                         f16* __restrict__ wrec2, unsigned int* __restrict__ hbuf_u32,
                         unsigned int* __restrict__ ctr) {
    const int i = blockIdx.x * blockDim.x + threadIdx.x;   // 0..524287
    const int dir = i >> 18;
    const int rem = i & 0x3FFFF;
    const int col = rem >> 8;        // 0..1023 : sl*128 + gg*32 + uu
    const int k   = rem & 255;
    const int sl  = col >> 7;
    const int gg  = (col & 127) >> 5;
    const int uu  = col & 31;
    const float* W = dir ? Wbw : Wfw;
    wrec2[i] = (f16)W[(size_t)(512 + k) * 1024 + gg * 256 + sl * 32 + uu];
    if (i < 32768) hbuf_u32[i] = 0u;   // h double-buffer (f16 zeros)
    if (i < 128) ctr[i] = 0u;          // barrier counters
}

// ---------------------------------------------------------------- xz GEMM
#define BM 128
#define BN 128
#define BK 32
#define ASTR 40   // f16 per LDS row (32 + 8 pad)

__global__ __launch_bounds__(256)
void gemm_xz(const float* __restrict__ x,
             const float* __restrict__ Wfw, const float* __restrict__ Wbw,
             const float* __restrict__ bfw, const float* __restrict__ bbw,
             f16* __restrict__ xz_fw, f16* __restrict__ xz_bw) {
    const int dir = blockIdx.z;
    const float* __restrict__ W    = dir ? Wbw : Wfw;
    const float* __restrict__ bias = dir ? bbw : bfw;
    f16* __restrict__ xz = dir ? xz_bw : xz_fw;

    __shared__ __align__(16) f16 As[BM * ASTR];
    __shared__ __align__(16) f16 Bs[BN * ASTR];

    const int tid = threadIdx.x;
    const int m0 = blockIdx.x * BM;
    const int n0 = blockIdx.y * BN;

    const int lane = tid & 63;
    const int wave = tid >> 6;
    const int wm = (wave & 1) * 64;
    const int wn = (wave >> 1) * 64;
    const int mi = lane & 15;
    const int kq = lane >> 4;

    const int arow = tid >> 1;
    const int ahalf = (tid & 1) * 16;
    const int am = m0 + arow;
    const int bb = am >> 9;            // batch (Tc=512)
    const int t  = am & 511;
    const int kk = tid >> 3;
    const int nc = (tid & 7) * 16;

    f32x4 acc[4][4];
#pragma unroll
    for (int i = 0; i < 4; i++)
#pragma unroll
        for (int j = 0; j < 4; j++) acc[i][j] = (f32x4)0.f;

    for (int kt = 0; kt < 512; kt += BK) {
        float va[16], vb[16];
        {
            const int kbase = kt + ahalf;
            const int hh = kbase >> 6;
            const float* px = x + (((size_t)bb * 8 + hh) * 512 + t) * 64 + (kbase & 63);
#pragma unroll
            for (int i = 0; i < 4; i++) {
                f32x4 v = *(const f32x4*)(px + i * 4);
                va[i*4+0] = v[0]; va[i*4+1] = v[1]; va[i*4+2] = v[2]; va[i*4+3] = v[3];
            }
            const float* pw = W + (size_t)(kt + kk) * 1024 + n0 + nc;
#pragma unroll
            for (int i = 0; i < 4; i++) {
                f32x4 v = *(const f32x4*)(pw + i * 4);
                vb[i*4+0] = v[0]; vb[i*4+1] = v[1]; vb[i*4+2] = v[2]; vb[i*4+3] = v[3];
            }
        }
        __syncthreads();
        {
            f16* pa = &As[arow * ASTR + ahalf];
#pragma unroll
            for (int i = 0; i < 4; i++) {
                f16x4 s;
                s[0] = (f16)va[i*4+0]; s[1] = (f16)va[i*4+1];
                s[2] = (f16)va[i*4+2]; s[3] = (f16)va[i*4+3];
                *(f16x4*)(pa + i * 4) = s;
            }
#pragma unroll
            for (int i = 0; i < 16; i++)
                Bs[(nc + i) * ASTR + kk] = (f16)vb[i];
        }
        __syncthreads();
        f16x8 afr[4], bfr[4];
#pragma unroll
        for (int mt = 0; mt < 4; mt++)
            afr[mt] = *(const f16x8*)(&As[(wm + mt * 16 + mi) * ASTR + kq * 8]);
#pragma unroll
        for (int nt = 0; nt < 4; nt++)
            bfr[nt] = *(const f16x8*)(&Bs[(wn + nt * 16 + mi) * ASTR + kq * 8]);
#pragma unroll
        for (int mt = 0; mt < 4; mt++)
#pragma unroll
            for (int nt = 0; nt < 4; nt++)
                acc[mt][nt] = __builtin_amdgcn_mfma_f32_16x16x32_f16(
                    afr[mt], bfr[nt], acc[mt][nt], 0, 0, 0);
    }

    const int col = lane & 15;
    const int rbase = kq * 4;
#pragma unroll
    for (int mt = 0; mt < 4; mt++) {
#pragma unroll
        for (int nt = 0; nt < 4; nt++) {
            const int n = n0 + wn + nt * 16 + col;
            const float bv = bias[n];
#pragma unroll
            for (int r = 0; r < 4; r++) {
                const int mrow = m0 + wm + mt * 16 + rbase + r;
                xz[(size_t)mrow * 1024 + n] = (f16)(acc[mt][nt][r] + bv);
            }
        }
    }
}

// ---------------------------------------------------------------- recurrence
// 16 wgs = 2 dirs x 8 slices; wg = 256 threads = 4 waves (2x2 tile split).
// Slice owns units [sl*32, sl*32+32) across all 4 gates (128 gate cols).
#define AP 272   // A_lds row stride (f16): 256 + 16 pad
#define ZP 67    // z_lds row stride (f32)

__global__ __launch_bounds__(256, 1)
void rec_persist(const f16* __restrict__ xz, const f16* __restrict__ wrec2,
                 f16* __restrict__ hbuf, unsigned int* __restrict__ ctr,
                 float* __restrict__ out) {
    const int bid = blockIdx.x;
    const int dir = bid >> 3;
    const int sl  = bid & 7;
    const f16* __restrict__ xzd = xz + (size_t)dir * 64 * 512 * 1024;
    const f16* __restrict__ wsl = wrec2 + ((size_t)dir * 1024 + sl * 128) * 256;
    f16* __restrict__ hbd = hbuf + (size_t)dir * 2 * 64 * 256;
    unsigned int* __restrict__ myc = ctr + dir * 64;

    __shared__ __align__(16) f16  A_lds[64 * AP];
    __shared__ float z_lds[128 * ZP];

    const int tid = threadIdx.x;
    const int lane = tid & 63;
    const int w = tid >> 6;
    const int r = w >> 1, c = w & 1;   // 2x2 wave tiling: r = m-half, c = n-half
    const int mi = lane & 15, kq = lane >> 4;

    // recurrent weight slab resident in registers: 32 frags = 128 VGPRs
    f16x8 Bf[4][8];
#pragma unroll
    for (int nt = 0; nt < 4; nt++)
#pragma unroll
        for (int ks = 0; ks < 8; ks++)
            Bf[nt][ks] = *(const f16x8*)(wsl + (size_t)(c * 64 + nt * 16 + mi) * 256
                                             + ks * 32 + kq * 8);

    const int b_act = tid >> 2;        // batch for activation phase
    const int ug = tid & 3;            // unit-octet within slice
    float cell[8];
#pragma unroll
    for (int j = 0; j < 8; j++) cell[j] = 0.f;

    const int sm = tid >> 2;           // staging: batch row
    const int sk = (tid & 3) * 64;     // staging: k range

    for (int s = 0; s < 512; s++) {
        const int t = dir ? (511 - s) : s;

        // ---- stage A = h(s-1) from MALL-coherent buffer into LDS ----
        const f16* hr = hbd + (s & 1) * (64 * 256);
        const u64* src = (const u64*)(hr + sm * 256 + sk);
        f16* dst = A_lds + sm * AP + sk;
#pragma unroll
        for (int i = 0; i < 16; i++) {
            u64 v = __hip_atomic_load(src + i, __ATOMIC_RELAXED, __HIP_MEMORY_SCOPE_AGENT);
            *(u64*)(dst + i * 4) = v;
        }
        // xz prefetch (held in regs through MFMA phase)
        f16x8 xzv[4];
        const f16* xp = xzd + ((size_t)b_act * 512 + t) * 1024 + sl * 32 + ug * 8;
#pragma unroll
        for (int g = 0; g < 4; g++) xzv[g] = *(const f16x8*)(xp + g * 256);

        __syncthreads();

        // ---- z = h @ Wrec (MFMA), wave tile 32m x 64n ----
        f32x4 acc[2][4];
#pragma unroll
        for (int mt = 0; mt < 2; mt++)
#pragma unroll
            for (int nt = 0; nt < 4; nt++) acc[mt][nt] = (f32x4)0.f;
#pragma unroll
        for (int ks = 0; ks < 8; ks++) {
            f16x8 Af[2];
#pragma unroll
            for (int mt = 0; mt < 2; mt++)
                Af[mt] = *(const f16x8*)(A_lds + (r * 32 + mt * 16 + mi) * AP
                                               + ks * 32 + kq * 8);
#pragma unroll
            for (int mt = 0; mt < 2; mt++)
#pragma unroll
                for (int nt = 0; nt < 4; nt++)
                    acc[mt][nt] = __builtin_amdgcn_mfma_f32_16x16x32_f16(
                        Af[mt], Bf[nt][ks], acc[mt][nt], 0, 0, 0);
        }
#pragma unroll
        for (int mt = 0; mt < 2; mt++)
#pragma unroll
            for (int nt = 0; nt < 4; nt++) {
                const int col = c * 64 + nt * 16 + mi;
                float* zp = z_lds + col * ZP + r * 32 + mt * 16 + kq * 4;
#pragma unroll
                for (int ri = 0; ri < 4; ri++) zp[ri] = acc[mt][nt][ri];
            }
        __syncthreads();

        // ---- activations: 8 cells per thread ----
        float hv[8];
#pragma unroll
        for (int j = 0; j < 8; j++) {
            const int uu = ug * 8 + j;
            const float zi = z_lds[(0 * 32 + uu) * ZP + b_act] + (float)xzv[0][j];
            const float zj = z_lds[(1 * 32 + uu) * ZP + b_act] + (float)xzv[1][j];
            const float zf = z_lds[(2 * 32 + uu) * ZP + b_act] + (float)xzv[2][j] + 1.0f;
            const float zo = z_lds[(3 * 32 + uu) * ZP + b_act] + (float)xzv[3][j];
            const float si = 1.f / (1.f + __expf(-zi));
            const float sf = 1.f / (1.f + __expf(-zf));
            const float so = 1.f / (1.f + __expf(-zo));
            const float tj = 1.f - 2.f / (1.f + __expf(2.f * zj));
            cell[j] = sf * cell[j] + si * tj;
            hv[j] = so * (1.f - 2.f / (1.f + __expf(2.f * cell[j])));
        }
        // h -> coherent buffer (f16, agent-scope so other XCDs see it)
        union { f16 h[8]; u64 q[2]; } up;
#pragma unroll
        for (int j = 0; j < 8; j++) up.h[j] = (f16)hv[j];
        f16* hwp = hbd + ((s + 1) & 1) * (64 * 256) + b_act * 256 + sl * 32 + ug * 8;
        __hip_atomic_store((u64*)hwp, up.q[0], __ATOMIC_RELAXED, __HIP_MEMORY_SCOPE_AGENT);
        __hip_atomic_store((u64*)hwp + 1, up.q[1], __ATOMIC_RELAXED, __HIP_MEMORY_SCOPE_AGENT);
        // out (fp32)
        float* op = out + ((size_t)b_act * 512 + t) * 512 + dir * 256 + sl * 32 + ug * 8;
        f32x4 o0 = {hv[0], hv[1], hv[2], hv[3]};
        f32x4 o1 = {hv[4], hv[5], hv[6], hv[7]};
        *(f32x4*)op = o0;
        *(f32x4*)(op + 4) = o1;

        // ---- inter-slice barrier (syncthreads drains vmcnt => h complete) ----
        __syncthreads();
        if (tid == 0) {
            __hip_atomic_fetch_add(myc, 1u, __ATOMIC_RELAXED, __HIP_MEMORY_SCOPE_AGENT);
            const unsigned tgt = 8u * (unsigned)(s + 1);
            while (__hip_atomic_load(myc, __ATOMIC_RELAXED, __HIP_MEMORY_SCOPE_AGENT) < tgt)
                __builtin_amdgcn_s_sleep(2);
        }
        __syncthreads();
    }
}

// ---------------------------------------------------------------- launcher
extern "C" void kernel_launch(void* const* d_in, const int* in_sizes, int n_in,
                              void* d_out, int out_size, void* d_ws, size_t ws_size,
                              hipStream_t stream) {
    const float* x   = (const float*)d_in[0];
    const float* Wfw = (const float*)d_in[1];
    const float* bfw = (const float*)d_in[2];
    const float* Wbw = (const float*)d_in[3];
    const float* bbw = (const float*)d_in[4];
    float* out = (float*)d_out;

    // ws layout (needs ~135.4 MB; round-1 confirmed ws >= 135.5 MB)
    f16* xzf   = (f16*)d_ws;                          // [64*512*1024]
    f16* xzb   = xzf + (size_t)64 * 512 * 1024;       // [64*512*1024]
    f16* wrec2 = xzb + (size_t)64 * 512 * 1024;       // [2*1024*256]
    f16* hbuf  = wrec2 + (size_t)2 * 1024 * 256;      // [2*2*64*256]
    unsigned int* ctr = (unsigned int*)(hbuf + (size_t)2 * 2 * 64 * 256);  // [128]

    init_all<<<dim3(2048), 256, 0, stream>>>(Wfw, Wbw, wrec2, (unsigned int*)hbuf, ctr);
    gemm_xz<<<dim3(256, 8, 2), 256, 0, stream>>>(x, Wfw, Wbw, bfw, bbw, xzf, xzb);
    rec_persist<<<dim3(16), 256, 0, stream>>>(xzf, wrec2, hbuf, ctr, out);

    (void)in_sizes; (void)n_in; (void)out_size; (void)ws_size;
}

// Round 3
// 2787.414 us; speedup vs baseline: 1.6887x; 1.2065x over previous
//
#include <hip/hip_runtime.h>

// Bidirectional LSTM: B=64, T=512, D=512 (feats k=h*64+c), U=256.
// W: [768,1024] fp32, gate order (i,j,f,o), forget bias 1.0.
// out [64,512,512] fp32 (fw units 0..255, bw 256..511), bw aligned to t.
//
//  init_all : repack recurrent weights -> wrec2[dir][128-col slice][k] f16,
//             zero h double-buffer + barrier counters.
//  gemm_xz  : xz[dir][b][t][1024] = feats@Wx + bias  (f16, MFMA 16x16x32)
//  rec_persist : 16 wgs (2 dirs x 8 slices). Weights in registers, h via
//             MALL-coherent agent-scope atomics, per-step all-thread spin.

typedef float f32x4 __attribute__((ext_vector_type(4)));
typedef _Float16 f16;
typedef _Float16 f16x4 __attribute__((ext_vector_type(4)));
typedef _Float16 f16x8 __attribute__((ext_vector_type(8)));
typedef unsigned long long u64;

// ---------------------------------------------------------------- init
__global__ void init_all(const float* __restrict__ Wfw, const float* __restrict__ Wbw,
                         f16* __restrict__ wrec2, unsigned int* __restrict__ hbuf_u32,
                         unsigned int* __restrict__ ctr) {
    const int i = blockIdx.x * blockDim.x + threadIdx.x;   // 0..524287
    const int dir = i >> 18;
    const int rem = i & 0x3FFFF;
    const int col = rem >> 8;        // 0..1023 : sl*128 + gg*32 + uu
    const int k   = rem & 255;
    const int sl  = col >> 7;
    const int gg  = (col & 127) >> 5;
    const int uu  = col & 31;
    const float* W = dir ? Wbw : Wfw;
    wrec2[i] = (f16)W[(size_t)(512 + k) * 1024 + gg * 256 + sl * 32 + uu];
    if (i < 32768) hbuf_u32[i] = 0u;   // h double-buffer (f16 zeros)
    if (i < 128) ctr[i] = 0u;          // barrier counters
}

// ---------------------------------------------------------------- xz GEMM
#define BM 128
#define BN 128
#define BK 32
#define ASTR 40   // f16 per LDS row (32 + 8 pad)

__global__ __launch_bounds__(256)
void gemm_xz(const float* __restrict__ x,
             const float* __restrict__ Wfw, const float* __restrict__ Wbw,
             const float* __restrict__ bfw, const float* __restrict__ bbw,
             f16* __restrict__ xz_fw, f16* __restrict__ xz_bw) {
    const int dir = blockIdx.z;
    const float* __restrict__ W    = dir ? Wbw : Wfw;
    const float* __restrict__ bias = dir ? bbw : bfw;
    f16* __restrict__ xz = dir ? xz_bw : xz_fw;

    __shared__ __align__(16) f16 As[BM * ASTR];
    __shared__ __align__(16) f16 Bs[BN * ASTR];

    const int tid = threadIdx.x;
    const int m0 = blockIdx.x * BM;
    const int n0 = blockIdx.y * BN;

    const int lane = tid & 63;
    const int wave = tid >> 6;
    const int wm = (wave & 1) * 64;
    const int wn = (wave >> 1) * 64;
    const int mi = lane & 15;
    const int kq = lane >> 4;

    const int arow = tid >> 1;
    const int ahalf = (tid & 1) * 16;
    const int am = m0 + arow;
    const int bb = am >> 9;            // batch (T=512)
    const int t  = am & 511;
    const int kk = tid >> 3;
    const int nc = (tid & 7) * 16;

    f32x4 acc[4][4];
#pragma unroll
    for (int i = 0; i < 4; i++)
#pragma unroll
        for (int j = 0; j < 4; j++) acc[i][j] = (f32x4)0.f;

    for (int kt = 0; kt < 512; kt += BK) {
        float va[16], vb[16];
        {
            const int kbase = kt + ahalf;
            const int hh = kbase >> 6;
            const float* px = x + (((size_t)bb * 8 + hh) * 512 + t) * 64 + (kbase & 63);
#pragma unroll
            for (int i = 0; i < 4; i++) {
                f32x4 v = *(const f32x4*)(px + i * 4);
                va[i*4+0] = v[0]; va[i*4+1] = v[1]; va[i*4+2] = v[2]; va[i*4+3] = v[3];
            }
            const float* pw = W + (size_t)(kt + kk) * 1024 + n0 + nc;
#pragma unroll
            for (int i = 0; i < 4; i++) {
                f32x4 v = *(const f32x4*)(pw + i * 4);
                vb[i*4+0] = v[0]; vb[i*4+1] = v[1]; vb[i*4+2] = v[2]; vb[i*4+3] = v[3];
            }
        }
        __syncthreads();
        {
            f16* pa = &As[arow * ASTR + ahalf];
#pragma unroll
            for (int i = 0; i < 4; i++) {
                f16x4 s;
                s[0] = (f16)va[i*4+0]; s[1] = (f16)va[i*4+1];
                s[2] = (f16)va[i*4+2]; s[3] = (f16)va[i*4+3];
                *(f16x4*)(pa + i * 4) = s;
            }
#pragma unroll
            for (int i = 0; i < 16; i++)
                Bs[(nc + i) * ASTR + kk] = (f16)vb[i];
        }
        __syncthreads();
        f16x8 afr[4], bfr[4];
#pragma unroll
        for (int mt = 0; mt < 4; mt++)
            afr[mt] = *(const f16x8*)(&As[(wm + mt * 16 + mi) * ASTR + kq * 8]);
#pragma unroll
        for (int nt = 0; nt < 4; nt++)
            bfr[nt] = *(const f16x8*)(&Bs[(wn + nt * 16 + mi) * ASTR + kq * 8]);
#pragma unroll
        for (int mt = 0; mt < 4; mt++)
#pragma unroll
            for (int nt = 0; nt < 4; nt++)
                acc[mt][nt] = __builtin_amdgcn_mfma_f32_16x16x32_f16(
                    afr[mt], bfr[nt], acc[mt][nt], 0, 0, 0);
    }

    const int col = lane & 15;
    const int rbase = kq * 4;
#pragma unroll
    for (int mt = 0; mt < 4; mt++) {
#pragma unroll
        for (int nt = 0; nt < 4; nt++) {
            const int n = n0 + wn + nt * 16 + col;
            const float bv = bias[n];
#pragma unroll
            for (int r = 0; r < 4; r++) {
                const int mrow = m0 + wm + mt * 16 + rbase + r;
                xz[(size_t)mrow * 1024 + n] = (f16)(acc[mt][nt][r] + bv);
            }
        }
    }
}

// ---------------------------------------------------------------- recurrence
// 16 wgs = 2 dirs x 8 slices; wg = 256 threads = 4 waves (2x2 tile split).
// Slice owns units [sl*32, sl*32+32) across all 4 gates (128 gate cols).
#define AP 264   // A_lds row stride (f16): 256 + 8 pad (2-way banks, free)
#define ZP 67    // z_lds row stride (f32)

__global__ __launch_bounds__(256, 1)
void rec_persist(const f16* __restrict__ xz, const f16* __restrict__ wrec2,
                 f16* __restrict__ hbuf, unsigned int* __restrict__ ctr,
                 float* __restrict__ out) {
    const int bid = blockIdx.x;
    const int dir = bid >> 3;
    const int sl  = bid & 7;
    const f16* __restrict__ xzd = xz + (size_t)dir * 64 * 512 * 1024;
    const f16* __restrict__ wsl = wrec2 + ((size_t)dir * 1024 + sl * 128) * 256;
    f16* __restrict__ hbd = hbuf + (size_t)dir * 2 * 64 * 256;
    unsigned int* __restrict__ myc = ctr + dir * 64;

    __shared__ __align__(16) f16  A_lds[64 * AP];
    __shared__ float z_lds[128 * ZP];

    const int tid = threadIdx.x;
    const int lane = tid & 63;
    const int w = tid >> 6;
    const int r = w >> 1, c = w & 1;   // 2x2 wave tiling
    const int mi = lane & 15, kq = lane >> 4;

    // recurrent weight slab resident in registers: 32 frags = 128 VGPRs
    f16x8 Bf[4][8];
#pragma unroll
    for (int nt = 0; nt < 4; nt++)
#pragma unroll
        for (int ks = 0; ks < 8; ks++)
            Bf[nt][ks] = *(const f16x8*)(wsl + (size_t)(c * 64 + nt * 16 + mi) * 256
                                             + ks * 32 + kq * 8);

    const int b_act = tid >> 2;        // batch for activation phase
    const int ug = tid & 3;            // unit-octet within slice
    float cell[8];
#pragma unroll
    for (int j = 0; j < 8; j++) cell[j] = 0.f;

    const int sm = tid >> 2;           // staging: batch row
    // staging: thread covers k = i*16 + ug*4 .. +4, i in [0,16)

    float pv[8];                       // deferred out values
    int   pt = 0;

    float* const outb = out + ((size_t)b_act * 512) * 512 + dir * 256 + sl * 32 + ug * 8;

    for (int s = 0; s < 512; s++) {
        const int t = dir ? (511 - s) : s;

        // ---- batched coherent loads of h(s-1): one pipelined MALL burst ----
        u64 va[16];
        {
            const u64* src = (const u64*)(hbd + (s & 1) * (64 * 256) + sm * 256);
#pragma unroll
            for (int i = 0; i < 16; i++)
                va[i] = __hip_atomic_load(src + i * 4 + ug, __ATOMIC_RELAXED,
                                          __HIP_MEMORY_SCOPE_AGENT);
        }
        // ---- deferred out store (prev step): drains in parallel with A loads
        if (s) {
            float* op = outb + (size_t)pt * 512;
            f32x4 o0 = {pv[0], pv[1], pv[2], pv[3]};
            f32x4 o1 = {pv[4], pv[5], pv[6], pv[7]};
            *(f32x4*)op = o0;
            *(f32x4*)(op + 4) = o1;
        }
        // ---- xz prefetch (held in regs through MFMA phase) ----
        f16x8 xzv[4];
        const f16* xp = xzd + ((size_t)b_act * 512 + t) * 1024 + sl * 32 + ug * 8;
#pragma unroll
        for (int g = 0; g < 4; g++) xzv[g] = *(const f16x8*)(xp + g * 256);

        // ---- A -> LDS ----
        {
            f16* dst = A_lds + sm * AP;
#pragma unroll
            for (int i = 0; i < 16; i++)
                *(u64*)(dst + i * 16 + ug * 4) = va[i];
        }
        __syncthreads();   // sync1

        // ---- z = h @ Wrec (MFMA), wave tile 32m x 64n ----
        f32x4 acc[2][4];
#pragma unroll
        for (int mt = 0; mt < 2; mt++)
#pragma unroll
            for (int nt = 0; nt < 4; nt++) acc[mt][nt] = (f32x4)0.f;
#pragma unroll
        for (int ks = 0; ks < 8; ks++) {
            f16x8 Af[2];
#pragma unroll
            for (int mt = 0; mt < 2; mt++)
                Af[mt] = *(const f16x8*)(A_lds + (r * 32 + mt * 16 + mi) * AP
                                               + ks * 32 + kq * 8);
#pragma unroll
            for (int mt = 0; mt < 2; mt++)
#pragma unroll
                for (int nt = 0; nt < 4; nt++)
                    acc[mt][nt] = __builtin_amdgcn_mfma_f32_16x16x32_f16(
                        Af[mt], Bf[nt][ks], acc[mt][nt], 0, 0, 0);
        }
#pragma unroll
        for (int mt = 0; mt < 2; mt++)
#pragma unroll
            for (int nt = 0; nt < 4; nt++) {
                const int col = c * 64 + nt * 16 + mi;
                float* zp = z_lds + col * ZP + r * 32 + mt * 16 + kq * 4;
#pragma unroll
                for (int ri = 0; ri < 4; ri++) zp[ri] = acc[mt][nt][ri];
            }
        __syncthreads();   // sync2

        // ---- activations: 8 cells per thread ----
        float hv[8];
#pragma unroll
        for (int j = 0; j < 8; j++) {
            const int uu = ug * 8 + j;
            const float zi = z_lds[(0 * 32 + uu) * ZP + b_act] + (float)xzv[0][j];
            const float zj = z_lds[(1 * 32 + uu) * ZP + b_act] + (float)xzv[1][j];
            const float zf = z_lds[(2 * 32 + uu) * ZP + b_act] + (float)xzv[2][j] + 1.0f;
            const float zo = z_lds[(3 * 32 + uu) * ZP + b_act] + (float)xzv[3][j];
            const float si = 1.f / (1.f + __expf(-zi));
            const float sf = 1.f / (1.f + __expf(-zf));
            const float so = 1.f / (1.f + __expf(-zo));
            const float tj = 1.f - 2.f / (1.f + __expf(2.f * zj));
            cell[j] = sf * cell[j] + si * tj;
            hv[j] = so * (1.f - 2.f / (1.f + __expf(2.f * cell[j])));
        }
        // h -> coherent buffer (f16, agent scope)
        union { f16 h[8]; u64 q[2]; } up;
#pragma unroll
        for (int j = 0; j < 8; j++) up.h[j] = (f16)hv[j];
        f16* hwp = hbd + ((s + 1) & 1) * (64 * 256) + b_act * 256 + sl * 32 + ug * 8;
        __hip_atomic_store((u64*)hwp, up.q[0], __ATOMIC_RELAXED, __HIP_MEMORY_SCOPE_AGENT);
        __hip_atomic_store((u64*)hwp + 1, up.q[1], __ATOMIC_RELAXED, __HIP_MEMORY_SCOPE_AGENT);
#pragma unroll
        for (int j = 0; j < 8; j++) pv[j] = hv[j];
        pt = t;

        // ---- sync3: drains h stores (all waves), then signal + all-thread spin
        __syncthreads();
        if (tid == 0)
            __hip_atomic_fetch_add(myc, 1u, __ATOMIC_RELAXED, __HIP_MEMORY_SCOPE_AGENT);
        const unsigned tgt = 8u * (unsigned)(s + 1);
        while (__hip_atomic_load(myc, __ATOMIC_RELAXED, __HIP_MEMORY_SCOPE_AGENT) < tgt)
            __builtin_amdgcn_s_sleep(1);
        // no barrier: A_lds writes are only consumed after sync1
    }
    // final deferred out store
    {
        float* op = outb + (size_t)pt * 512;
        f32x4 o0 = {pv[0], pv[1], pv[2], pv[3]};
        f32x4 o1 = {pv[4], pv[5], pv[6], pv[7]};
        *(f32x4*)op = o0;
        *(f32x4*)(op + 4) = o1;
    }
}

// ---------------------------------------------------------------- launcher
extern "C" void kernel_launch(void* const* d_in, const int* in_sizes, int n_in,
                              void* d_out, int out_size, void* d_ws, size_t ws_size,
                              hipStream_t stream) {
    const float* x   = (const float*)d_in[0];
    const float* Wfw = (const float*)d_in[1];
    const float* bfw = (const float*)d_in[2];
    const float* Wbw = (const float*)d_in[3];
    const float* bbw = (const float*)d_in[4];
    float* out = (float*)d_out;

    f16* xzf   = (f16*)d_ws;                          // [64*512*1024]
    f16* xzb   = xzf + (size_t)64 * 512 * 1024;       // [64*512*1024]
    f16* wrec2 = xzb + (size_t)64 * 512 * 1024;       // [2*1024*256]
    f16* hbuf  = wrec2 + (size_t)2 * 1024 * 256;      // [2*2*64*256]
    unsigned int* ctr = (unsigned int*)(hbuf + (size_t)2 * 2 * 64 * 256);  // [128]

    init_all<<<dim3(2048), 256, 0, stream>>>(Wfw, Wbw, wrec2, (unsigned int*)hbuf, ctr);
    gemm_xz<<<dim3(256, 8, 2), 256, 0, stream>>>(x, Wfw, Wbw, bfw, bbw, xzf, xzb);
    rec_persist<<<dim3(16), 256, 0, stream>>>(xzf, wrec2, hbuf, ctr, out);

    (void)in_sizes; (void)n_in; (void)out_size; (void)ws_size;
}